// Round 1
// baseline (233.431 us; speedup 1.0000x reference)
//
#include <hip/hip_runtime.h>

// Problem constants
#define BB 16
#define CC 2048
#define HH 32
#define WW 32
#define HW 1024   // H*W
#define NP 64     // n_points

// ws layout (floats):
//   q:      [BB][NP][CC]   = 2,097,152 floats (8 MB)   -- normalized queries, row-major over c
//   norms2: [BB][HW]       =    16,384 floats (64 KB)  -- sum of squares of key vectors
//   dot:    [BB][NP][HW]   = 1,048,576 floats (4 MB)   -- raw q-hat . fea dot products

// ---------------------------------------------------------------------------
// Kernel A: gather queries at point locations, normalize over c, write q.
// grid = (NP, BB), block = 256
// ---------------------------------------------------------------------------
__global__ __launch_bounds__(256) void query_kernel(const float* __restrict__ fea,
                                                    const float* __restrict__ pl,
                                                    float* __restrict__ q) {
    int p = blockIdx.x;
    int b = blockIdx.y;
    int tid = threadIdx.x;

    float px = pl[p * 2 + 0];
    float py = pl[p * 2 + 1];
    int ix = (int)(px * WW); ix = min(max(ix, 0), WW - 1);
    int iy = (int)(py * HH); iy = min(max(iy, 0), HH - 1);
    int kp = iy * WW + ix;

    const float* fb = fea + (size_t)b * CC * HW + kp;

    float v[8];
    float ssq = 0.f;
#pragma unroll
    for (int j = 0; j < 8; ++j) {
        int c = j * 256 + tid;
        v[j] = fb[(size_t)c * HW];
        ssq += v[j] * v[j];
    }

    // block reduction (4 waves of 64)
    __shared__ float red[4];
#pragma unroll
    for (int off = 32; off; off >>= 1) ssq += __shfl_xor(ssq, off);
    int wave = tid >> 6;
    if ((tid & 63) == 0) red[wave] = ssq;
    __syncthreads();
    float total = red[0] + red[1] + red[2] + red[3];
    float rn = rsqrtf(total);

    float* qrow = q + (size_t)(b * NP + p) * CC;
#pragma unroll
    for (int j = 0; j < 8; ++j) {
        int c = j * 256 + tid;
        qrow[c] = v[j] * rn;
    }
}

// ---------------------------------------------------------------------------
// Kernel B: batched GEMM dot[b][p][k] += sum_c q[b][p][c] * fea[b][c][k]
// fused with key sum-of-squares accumulation (wave 0 only).
// grid = (4 k-chunks, 8 c-chunks, BB), block = 256
// Thread tiling: 4 consecutive k, 16 p -> 64 fp32 accumulators.
// ---------------------------------------------------------------------------
__global__ __launch_bounds__(256) void gemm_kernel(const float* __restrict__ fea,
                                                   const float* __restrict__ q,
                                                   float* __restrict__ norms2,
                                                   float* __restrict__ dot) {
    int kc  = blockIdx.x;   // 0..3   (k chunk of 256)
    int cch = blockIdx.y;   // 0..7   (c chunk of 256)
    int b   = blockIdx.z;

    int tid = threadIdx.x;
    int kg = tid & 63;      // 0..63 within wave
    int pg = tid >> 6;      // wave index 0..3
    int k0 = kc * 256 + kg * 4;
    int p0 = pg * 16;
    int c0 = cch * 256;

    __shared__ float qs[16][68];   // padded to avoid write-phase bank conflicts

    float acc[4][16];
#pragma unroll
    for (int m = 0; m < 4; ++m)
#pragma unroll
        for (int pp = 0; pp < 16; ++pp) acc[m][pp] = 0.f;
    float ssq[4] = {0.f, 0.f, 0.f, 0.f};

    const float* fb = fea + (size_t)b * CC * HW + k0;
    const float* qb = q + (size_t)b * NP * CC;

    for (int ct = 0; ct < 256; ct += 16) {
        int cbase = c0 + ct;
        // stage q tile: 16 c x 64 p  (transpose while storing)
        {
            int pr = tid >> 2;          // 0..63 : point row
            int quad = tid & 3;         // 0..3  : which 4-c group
            const float4 qv = *(const float4*)(qb + (size_t)pr * CC + cbase + quad * 4);
            qs[quad * 4 + 0][pr] = qv.x;
            qs[quad * 4 + 1][pr] = qv.y;
            qs[quad * 4 + 2][pr] = qv.z;
            qs[quad * 4 + 3][pr] = qv.w;
        }
        __syncthreads();

#pragma unroll
        for (int cc = 0; cc < 16; ++cc) {
            int c = cbase + cc;
            float4 fv = *(const float4*)(fb + (size_t)c * HW);
            float f[4] = {fv.x, fv.y, fv.z, fv.w};
            if (pg == 0) {   // wave-uniform branch: wave 0 owns all 256 k once
#pragma unroll
                for (int m = 0; m < 4; ++m) ssq[m] += f[m] * f[m];
            }
#pragma unroll
            for (int pp = 0; pp < 16; pp += 4) {
                float4 qv = *(const float4*)&qs[cc][p0 + pp];
                float qa[4] = {qv.x, qv.y, qv.z, qv.w};
#pragma unroll
                for (int m = 0; m < 4; ++m) {
#pragma unroll
                    for (int j = 0; j < 4; ++j) acc[m][pp + j] += f[m] * qa[j];
                }
            }
        }
        __syncthreads();
    }

    // epilogue
    if (pg == 0) {
#pragma unroll
        for (int m = 0; m < 4; ++m)
            atomicAdd(&norms2[b * HW + k0 + m], ssq[m]);
    }
#pragma unroll
    for (int pp = 0; pp < 16; ++pp) {
#pragma unroll
        for (int m = 0; m < 4; ++m) {
            atomicAdd(&dot[(size_t)(b * NP + p0 + pp) * HW + k0 + m], acc[m][pp]);
        }
    }
}

// ---------------------------------------------------------------------------
// Kernel C: finalize. val = dot / sqrt(norms2); per-(b,p) min/max over k;
// out = valid ? (val - amin) / amax : 0
// grid = (NP, BB), block = 256, 4 k per thread
// ---------------------------------------------------------------------------
__global__ __launch_bounds__(256) void finalize_kernel(const float* __restrict__ dot,
                                                       const float* __restrict__ norms2,
                                                       const int* __restrict__ valid,
                                                       float* __restrict__ out) {
    int p = blockIdx.x;
    int b = blockIdx.y;
    int tid = threadIdx.x;
    int k0 = tid * 4;

    float4 d  = *(const float4*)(dot + (size_t)(b * NP + p) * HW + k0);
    float4 n2 = *(const float4*)(norms2 + b * HW + k0);

    float val[4];
    val[0] = d.x * rsqrtf(n2.x);
    val[1] = d.y * rsqrtf(n2.y);
    val[2] = d.z * rsqrtf(n2.z);
    val[3] = d.w * rsqrtf(n2.w);

    float mn = fminf(fminf(val[0], val[1]), fminf(val[2], val[3]));
    float mx = fmaxf(fmaxf(val[0], val[1]), fmaxf(val[2], val[3]));

#pragma unroll
    for (int off = 32; off; off >>= 1) {
        mn = fminf(mn, __shfl_xor(mn, off));
        mx = fmaxf(mx, __shfl_xor(mx, off));
    }
    __shared__ float smn[4], smx[4];
    int wave = tid >> 6;
    if ((tid & 63) == 0) { smn[wave] = mn; smx[wave] = mx; }
    __syncthreads();
    mn = fminf(fminf(smn[0], smn[1]), fminf(smn[2], smn[3]));
    mx = fmaxf(fmaxf(smx[0], smx[1]), fmaxf(smx[2], smx[3]));

    bool vld = valid[p] != 0;
    float4 o;
    o.x = vld ? (val[0] - mn) / mx : 0.f;
    o.y = vld ? (val[1] - mn) / mx : 0.f;
    o.z = vld ? (val[2] - mn) / mx : 0.f;
    o.w = vld ? (val[3] - mn) / mx : 0.f;
    *(float4*)(out + (size_t)(b * NP + p) * HW + k0) = o;
}

// ---------------------------------------------------------------------------
extern "C" void kernel_launch(void* const* d_in, const int* in_sizes, int n_in,
                              void* d_out, int out_size, void* d_ws, size_t ws_size,
                              hipStream_t stream) {
    const float* fea = (const float*)d_in[0];
    const float* pl  = (const float*)d_in[1];
    const int* valid = (const int*)d_in[2];
    float* out = (float*)d_out;

    float* q      = (float*)d_ws;                       // 2,097,152 floats
    float* norms2 = q + (size_t)BB * NP * CC;           // 16,384 floats
    float* dot    = norms2 + BB * HW;                   // 1,048,576 floats

    // zero the atomic accumulation buffers (norms2 + dot are contiguous)
    hipMemsetAsync(norms2, 0, (size_t)(BB * HW + BB * NP * HW) * sizeof(float), stream);

    query_kernel<<<dim3(NP, BB), 256, 0, stream>>>(fea, pl, q);
    gemm_kernel<<<dim3(4, 8, BB), 256, 0, stream>>>(fea, q, norms2, dot);
    finalize_kernel<<<dim3(NP, BB), 256, 0, stream>>>(dot, norms2, valid, out);
}

// Round 2
// 79.329 us; speedup vs baseline: 2.9426x; 2.9426x over previous
//
#include <hip/hip_runtime.h>

// Problem constants
#define BB 16
#define CC 2048
#define HH 32
#define WW 32
#define HW 1024   // H*W
#define NP 64     // n_points

// GEMM tiling
#define KB 32          // spatial-k per block
#define CT 32          // c per K-step
#define CS 2           // c-split (partial dot buffers)
#define CHALF (CC/CS)  // 1024
#define NSTEP (CHALF/CT)
#define BPITCH 36      // LDS k-pitch in bf16 elems (72 B)

typedef __bf16 bf16x8 __attribute__((ext_vector_type(8)));
typedef float  f32x4  __attribute__((ext_vector_type(4)));

__device__ __forceinline__ unsigned short f2bf(float x) {
    unsigned u = __float_as_uint(x);
    u += 0x7fffu + ((u >> 16) & 1u);   // round-to-nearest-even
    return (unsigned short)(u >> 16);
}

// ws layout:
//   qbf:    [BB][NP][CC]  bf16   = 4 MiB   (raw gathered queries, NOT normalized)
//   norms2: [BB][HW]      fp32   = 64 KiB  (key/query sum-of-squares, exact fp32)
//   dotp:   [CS][BB][NP][HW] f32 = 8 MiB   (partial raw dot products)

// ---------------------------------------------------------------------------
// Kernel A: pure gather fea[b, :, kp] -> qbf[b][p][:], bf16. No normalization.
// ---------------------------------------------------------------------------
__global__ __launch_bounds__(256) void gather_kernel(const float* __restrict__ fea,
                                                     const float* __restrict__ pl,
                                                     unsigned short* __restrict__ qbf) {
    int p = blockIdx.x;
    int b = blockIdx.y;
    int tid = threadIdx.x;

    int ix = (int)(pl[p * 2 + 0] * WW); ix = min(max(ix, 0), WW - 1);
    int iy = (int)(pl[p * 2 + 1] * HH); iy = min(max(iy, 0), HH - 1);
    int kp = iy * WW + ix;

    const float* fb = fea + (size_t)b * CC * HW + kp;
    unsigned short* qrow = qbf + (size_t)(b * NP + p) * CC;
#pragma unroll
    for (int j = 0; j < 8; ++j) {
        int c = j * 256 + tid;
        qrow[c] = f2bf(fb[(size_t)c * HW]);
    }
}

// ---------------------------------------------------------------------------
// Kernel B: MFMA GEMM. dotp[cs][b][p][k] = sum_{c in half} q[p][c] * fea[c][k]
// fused with exact fp32 key sum-of-squares (atomicAdd, 2 adds per location).
// grid = (HW/KB, CS, BB), block = 256 (4 waves). Wave w owns p-rows [16w,16w+16),
// both 16-wide k-tiles of the block's 32-k slab.
// ---------------------------------------------------------------------------
__global__ __launch_bounds__(256) void gemm_kernel(const float* __restrict__ fea,
                                                   const unsigned short* __restrict__ qbf,
                                                   float* __restrict__ norms2,
                                                   float* __restrict__ dotp) {
    int kc = blockIdx.x;
    int cs = blockIdx.y;
    int b  = blockIdx.z;

    int tid  = threadIdx.x;
    int lane = tid & 63;
    int w    = tid >> 6;          // wave id -> p tile
    int p0   = w * 16;
    int k0   = kc * KB;
    int c0   = cs * CHALF;

    __shared__ __align__(16) unsigned short bt[CT][BPITCH];   // bf16 fea tile [c][k]
    __shared__ float red[CT][KB];                              // ssq reduction scratch

    // staging assignment: thread reads fea[c0+s*CT+cr][k0+4*kq .. +3]
    int cr = tid >> 3;            // 0..31
    int kq = tid & 7;             // 0..7
    const float* fptr = fea + ((size_t)b * CC + c0 + cr) * HW + k0 + 4 * kq;

    // A fragment: lane needs q[p0 + (lane&15)][c0 + 8*(lane>>4) + e], e=0..7
    const unsigned short* qptr = qbf + (size_t)(b * NP + p0 + (lane & 15)) * CC
                                 + c0 + 8 * (lane >> 4);

    int gi = lane >> 4;           // 0..3 : c-octet group
    int ii = lane & 15;           // 0..15: k column within tile

    f32x4 acc0 = {0.f, 0.f, 0.f, 0.f};
    f32x4 acc1 = {0.f, 0.f, 0.f, 0.f};
    float ssq[4] = {0.f, 0.f, 0.f, 0.f};

    for (int s = 0; s < NSTEP; ++s) {
        // issue global loads early (overlap with previous step's compute)
        float4 fv = *(const float4*)fptr;
        fptr += (size_t)CT * HW;

        union { int4 i; bf16x8 v; } au;
        au.i = *(const int4*)qptr;
        qptr += CT;

        __syncthreads();   // previous tile's reads complete
        // convert + stage
        {
            unsigned h0 = f2bf(fv.x), h1 = f2bf(fv.y), h2 = f2bf(fv.z), h3 = f2bf(fv.w);
            uint2 packed = make_uint2(h0 | (h1 << 16), h2 | (h3 << 16));
            *(uint2*)&bt[cr][4 * kq] = packed;
            ssq[0] += fv.x * fv.x; ssq[1] += fv.y * fv.y;
            ssq[2] += fv.z * fv.z; ssq[3] += fv.w * fv.w;
        }
        __syncthreads();   // tile visible

        // B fragments: lane l holds B[c = 8*gi + e][k = 16*kt + ii]
        union { unsigned short u[8]; bf16x8 v; } b0, b1;
#pragma unroll
        for (int e = 0; e < 8; ++e) {
            b0.u[e] = bt[8 * gi + e][ii];
            b1.u[e] = bt[8 * gi + e][16 + ii];
        }
        acc0 = __builtin_amdgcn_mfma_f32_16x16x32_bf16(au.v, b0.v, acc0, 0, 0, 0);
        acc1 = __builtin_amdgcn_mfma_f32_16x16x32_bf16(au.v, b1.v, acc1, 0, 0, 0);
    }

    // ---- store partial dots (D layout: col = lane&15, row = 4*(lane>>4)+r) ----
    float* dbase = dotp + (((size_t)cs * BB + b) * NP) * HW;
#pragma unroll
    for (int r = 0; r < 4; ++r) {
        int p = p0 + 4 * gi + r;
        dbase[(size_t)p * HW + k0 + ii]      = acc0[r];
        dbase[(size_t)p * HW + k0 + 16 + ii] = acc1[r];
    }

    // ---- ssq reduction: red[cr][k_local] ----
    __syncthreads();
    *(float4*)&red[cr][4 * kq] = make_float4(ssq[0], ssq[1], ssq[2], ssq[3]);
    __syncthreads();
    if (tid < KB) {
        float s = 0.f;
#pragma unroll
        for (int r = 0; r < CT; ++r) s += red[r][tid];
        atomicAdd(&norms2[b * HW + k0 + tid], s);
    }
}

// ---------------------------------------------------------------------------
// Kernel C: finalize. val = (d0+d1)*rsqrt(n2[kp]*n2[k]); min/max over k;
// out = valid ? (val - amin)/amax : 0
// ---------------------------------------------------------------------------
__global__ __launch_bounds__(256) void finalize_kernel(const float* __restrict__ dotp,
                                                       const float* __restrict__ norms2,
                                                       const float* __restrict__ pl,
                                                       const int* __restrict__ valid,
                                                       float* __restrict__ out) {
    int p = blockIdx.x;
    int b = blockIdx.y;
    int tid = threadIdx.x;
    int k0 = tid * 4;

    int ix = (int)(pl[p * 2 + 0] * WW); ix = min(max(ix, 0), WW - 1);
    int iy = (int)(pl[p * 2 + 1] * HH); iy = min(max(iy, 0), HH - 1);
    int kp = iy * WW + ix;
    float n2p = norms2[b * HW + kp];

    const float* d0 = dotp + (((size_t)0 * BB + b) * NP + p) * HW;
    const float* d1 = dotp + (((size_t)1 * BB + b) * NP + p) * HW;
    float4 a = *(const float4*)(d0 + k0);
    float4 c = *(const float4*)(d1 + k0);
    float4 n2 = *(const float4*)(norms2 + b * HW + k0);

    float val[4];
    val[0] = (a.x + c.x) * rsqrtf(n2p * n2.x);
    val[1] = (a.y + c.y) * rsqrtf(n2p * n2.y);
    val[2] = (a.z + c.z) * rsqrtf(n2p * n2.z);
    val[3] = (a.w + c.w) * rsqrtf(n2p * n2.w);

    float mn = fminf(fminf(val[0], val[1]), fminf(val[2], val[3]));
    float mx = fmaxf(fmaxf(val[0], val[1]), fmaxf(val[2], val[3]));
#pragma unroll
    for (int off = 32; off; off >>= 1) {
        mn = fminf(mn, __shfl_xor(mn, off));
        mx = fmaxf(mx, __shfl_xor(mx, off));
    }
    __shared__ float smn[4], smx[4];
    int wave = tid >> 6;
    if ((tid & 63) == 0) { smn[wave] = mn; smx[wave] = mx; }
    __syncthreads();
    mn = fminf(fminf(smn[0], smn[1]), fminf(smn[2], smn[3]));
    mx = fmaxf(fmaxf(smx[0], smx[1]), fmaxf(smx[2], smx[3]));

    bool vld = valid[p] != 0;
    float4 o;
    o.x = vld ? (val[0] - mn) / mx : 0.f;
    o.y = vld ? (val[1] - mn) / mx : 0.f;
    o.z = vld ? (val[2] - mn) / mx : 0.f;
    o.w = vld ? (val[3] - mn) / mx : 0.f;
    *(float4*)(out + (size_t)(b * NP + p) * HW + k0) = o;
}

// ---------------------------------------------------------------------------
extern "C" void kernel_launch(void* const* d_in, const int* in_sizes, int n_in,
                              void* d_out, int out_size, void* d_ws, size_t ws_size,
                              hipStream_t stream) {
    const float* fea = (const float*)d_in[0];
    const float* pl  = (const float*)d_in[1];
    const int* valid = (const int*)d_in[2];
    float* out = (float*)d_out;

    unsigned short* qbf = (unsigned short*)d_ws;                 // 4 MiB
    float* norms2 = (float*)(qbf + (size_t)BB * NP * CC);        // 64 KiB
    float* dotp   = norms2 + (size_t)BB * HW;                    // 8 MiB

    hipMemsetAsync(norms2, 0, (size_t)BB * HW * sizeof(float), stream);

    gather_kernel<<<dim3(NP, BB), 256, 0, stream>>>(fea, pl, qbf);
    gemm_kernel<<<dim3(HW / KB, CS, BB), 256, 0, stream>>>(fea, qbf, norms2, dotp);
    finalize_kernel<<<dim3(NP, BB), 256, 0, stream>>>(dotp, norms2, pl, valid, out);
}

// Round 3
// 58.687 us; speedup vs baseline: 3.9775x; 1.3517x over previous
//
#include <hip/hip_runtime.h>

// Problem constants
#define BB 16
#define CC 2048
#define HH 32
#define WW 32
#define HW 1024   // H*W
#define NP 64     // n_points

// prep tiling
#define PCH 32            // c-rows per prep block
#define NCH (CC/PCH)      // 64 chunks

// gemm tiling
#define KB 32             // spatial-k per gemm block
#define CT 64             // c per K-step
#define NSTEP (CC/CT)     // 32
#define BP 36             // LDS k-pitch in bf16 elems (72 B, pad kills stride-64B conflicts)

typedef __bf16 bf16x8 __attribute__((ext_vector_type(8)));
typedef float  f32x4  __attribute__((ext_vector_type(4)));

__device__ __forceinline__ unsigned f2bf2(float lo, float hi) {
    // pack two fp32 -> two RNE bf16 in one u32
    unsigned a = __float_as_uint(lo);
    unsigned b = __float_as_uint(hi);
    a += 0x7fffu + ((a >> 16) & 1u);
    b += 0x7fffu + ((b >> 16) & 1u);
    return (a >> 16) | (b & 0xffff0000u);
}

// ws layout:
//   qbf: [BB][NP][CC] bf16          = 4 MiB  (gathered queries, bf16(fea) columns)
//   np2: [NCH][BB][HW] f32          = 4 MiB  (partial key sum-of-squares, non-atomic)
//   rn:  [BB][HW] f32               = 64 KiB (rsqrt of key norms^2)
//   dot: [BB][NP][HW] f32           = 4 MiB  (raw bf16-GEMM dot products)

// ---------------------------------------------------------------------------
// Kernel 1: coalesced fea scan. Per (b, 32-row c-chunk):
//   - exact fp32 ssq partials  -> np2[cch][b][k]   (plain coalesced stores)
//   - query extraction via LDS -> qbf[b][p][c]     (bf16, coalesced stores)
// grid = (NCH, BB), block = 256 (4 waves; wave = one c-row per phase)
// ---------------------------------------------------------------------------
__global__ __launch_bounds__(256) void prep_kernel(const float* __restrict__ fea,
                                                   const float* __restrict__ pl,
                                                   unsigned short* __restrict__ qbf,
                                                   float* __restrict__ np2) {
    int cch = blockIdx.x, b = blockIdx.y;
    int t = threadIdx.x, lane = t & 63, rr = t >> 6;

    // point index for p = lane (used in extraction)
    int ix = (int)(pl[2 * lane + 0] * WW); ix = min(max(ix, 0), WW - 1);
    int iy = (int)(pl[2 * lane + 1] * HH); iy = min(max(iy, 0), HH - 1);
    int kp = iy * WW + ix;

    __shared__ unsigned short buf[2][4][HW];     // 16 KiB, double-buffered 4-row bf16 tile
    __shared__ unsigned short ex[NP][PCH + 4];   // 4.5 KiB, extracted queries [p][c_local]

    float ssq[16];
#pragma unroll
    for (int i = 0; i < 16; ++i) ssq[i] = 0.f;

    const float* base = fea + ((size_t)b * CC + cch * PCH + rr) * HW + 4 * lane;

#pragma unroll
    for (int ph = 0; ph < PCH / 4; ++ph) {       // 8 phases x 4 rows
        float4 fv[4];
#pragma unroll
        for (int s = 0; s < 4; ++s)
            fv[s] = *(const float4*)(base + (size_t)(ph * 4) * HW + 256 * s);
#pragma unroll
        for (int s = 0; s < 4; ++s) {
            ssq[4 * s + 0] += fv[s].x * fv[s].x;
            ssq[4 * s + 1] += fv[s].y * fv[s].y;
            ssq[4 * s + 2] += fv[s].z * fv[s].z;
            ssq[4 * s + 3] += fv[s].w * fv[s].w;
            uint2 pk;
            pk.x = f2bf2(fv[s].x, fv[s].y);
            pk.y = f2bf2(fv[s].z, fv[s].w);
            *(uint2*)&buf[ph & 1][rr][4 * lane + 256 * s] = pk;
        }
        __syncthreads();
        // extraction: thread (rr, p=lane) pulls its point's column from row rr
        ex[lane][ph * 4 + rr] = buf[ph & 1][rr][kp];
        // no second barrier: next phase writes the OTHER buffer; 2-ahead writes
        // are fenced by the next iteration's barrier.
    }
    __syncthreads();

    // cross-wave ssq reduce, reusing buf as float red[4][HW] (exactly 16 KiB)
    float* red = (float*)buf;
#pragma unroll
    for (int s = 0; s < 4; ++s) {
        f32x4 v = {ssq[4 * s + 0], ssq[4 * s + 1], ssq[4 * s + 2], ssq[4 * s + 3]};
        *(f32x4*)&red[rr * HW + 4 * lane + 256 * s] = v;
    }
    __syncthreads();
    {
        int k0 = 4 * t;
        f32x4 r0 = *(f32x4*)&red[0 * HW + k0];
        f32x4 r1 = *(f32x4*)&red[1 * HW + k0];
        f32x4 r2 = *(f32x4*)&red[2 * HW + k0];
        f32x4 r3 = *(f32x4*)&red[3 * HW + k0];
        f32x4 sum = (r0 + r1) + (r2 + r3);
        *(f32x4*)&np2[((size_t)cch * BB + b) * HW + k0] = sum;
    }
    // qbf write: thread t -> p = t>>2, 8 c-values
    {
        int p = t >> 2, part = t & 3;
        uint2 lo = *(uint2*)&ex[p][8 * part];
        uint2 hi = *(uint2*)&ex[p][8 * part + 4];
        uint4 o = make_uint4(lo.x, lo.y, hi.x, hi.y);
        *(uint4*)&qbf[((size_t)b * NP + p) * CC + cch * PCH + 8 * part] = o;
    }
}

// ---------------------------------------------------------------------------
// Kernel 2: reduce np2 partials -> rn = rsqrt(sum). grid = (BB), block = 256.
// ---------------------------------------------------------------------------
__global__ __launch_bounds__(256) void nred_kernel(const float* __restrict__ np2,
                                                   float* __restrict__ rn) {
    int b = blockIdx.x;
    int k0 = 4 * threadIdx.x;
    f32x4 s = {0.f, 0.f, 0.f, 0.f};
#pragma unroll 8
    for (int cch = 0; cch < NCH; ++cch)
        s += *(const f32x4*)&np2[((size_t)cch * BB + b) * HW + k0];
    f32x4 r;
    r[0] = rsqrtf(s[0]); r[1] = rsqrtf(s[1]);
    r[2] = rsqrtf(s[2]); r[3] = rsqrtf(s[3]);
    *(f32x4*)&rn[(size_t)b * HW + k0] = r;
}

// ---------------------------------------------------------------------------
// Kernel 3: bf16 MFMA GEMM. dot[b][p][k] = sum_c q[p][c] * fea[c][k]
// fea re-read is L3-resident after prep's scan. One barrier per K-step,
// ping-pong LDS, global loads prefetched one step ahead.
// grid = (HW/KB, BB), block = 256 (wave w owns p-rows [16w, 16w+16))
// ---------------------------------------------------------------------------
__global__ __launch_bounds__(256) void gemm_kernel(const float* __restrict__ fea,
                                                   const unsigned short* __restrict__ qbf,
                                                   float* __restrict__ dot) {
    int kc = blockIdx.x, b = blockIdx.y;
    int t = threadIdx.x, lane = t & 63, w = t >> 6;
    int p0 = 16 * w, k0 = KB * kc;
    int gi = lane >> 4, ii = lane & 15;

    __shared__ unsigned short bt[2][CT][BP];   // 9 KiB

    int c = t >> 2, q = t & 3;                 // staging: row c, 2x float4 per thread
    const float* gsrc = fea + ((size_t)b * CC + c) * HW + k0 + 4 * q;
    const unsigned short* arow = qbf + ((size_t)b * NP + p0 + ii) * CC + 8 * gi;

    f32x4 acc0 = {0.f, 0.f, 0.f, 0.f}, acc1 = {0.f, 0.f, 0.f, 0.f};

    union U8 { int4 i; bf16x8 v; };
    float4 ga = *(const float4*)(gsrc);
    float4 gb = *(const float4*)(gsrc + 16);
    U8 au0, au1, na0, na1;
    au0.i = *(const int4*)(arow);
    au1.i = *(const int4*)(arow + 32);

    for (int s = 0; s < NSTEP; ++s) {
        int cur = s & 1;
        uint2 pk0, pk1;
        pk0.x = f2bf2(ga.x, ga.y); pk0.y = f2bf2(ga.z, ga.w);
        pk1.x = f2bf2(gb.x, gb.y); pk1.y = f2bf2(gb.z, gb.w);
        *(uint2*)&bt[cur][c][4 * q]      = pk0;
        *(uint2*)&bt[cur][c][16 + 4 * q] = pk1;
        __syncthreads();

        if (s + 1 < NSTEP) {   // prefetch next step (in flight under MFMA)
            ga = *(const float4*)(gsrc + (size_t)(s + 1) * CT * HW);
            gb = *(const float4*)(gsrc + (size_t)(s + 1) * CT * HW + 16);
            na0.i = *(const int4*)(arow + (s + 1) * CT);
            na1.i = *(const int4*)(arow + (s + 1) * CT + 32);
        }

#pragma unroll
        for (int h = 0; h < 2; ++h) {
            union { unsigned short u[8]; bf16x8 v; } b0, b1;
#pragma unroll
            for (int e = 0; e < 8; ++e) {
                b0.u[e] = bt[cur][32 * h + 8 * gi + e][ii];
                b1.u[e] = bt[cur][32 * h + 8 * gi + e][16 + ii];
            }
            bf16x8 A = h ? au1.v : au0.v;
            acc0 = __builtin_amdgcn_mfma_f32_16x16x32_bf16(A, b0.v, acc0, 0, 0, 0);
            acc1 = __builtin_amdgcn_mfma_f32_16x16x32_bf16(A, b1.v, acc1, 0, 0, 0);
        }
        au0 = na0; au1 = na1;
    }

    float* dbase = dot + ((size_t)b * NP) * HW;
#pragma unroll
    for (int r = 0; r < 4; ++r) {
        int p = p0 + 4 * gi + r;
        dbase[(size_t)p * HW + k0 + ii]      = acc0[r];
        dbase[(size_t)p * HW + k0 + 16 + ii] = acc1[r];
    }
}

// ---------------------------------------------------------------------------
// Kernel 4: finalize. val = dot * rn[k] * rn[kp]; min/max over k;
// out = valid ? (val - amin)/amax : 0.  grid = (NP, BB), block = 256.
// ---------------------------------------------------------------------------
__global__ __launch_bounds__(256) void finalize_kernel(const float* __restrict__ dot,
                                                       const float* __restrict__ rn,
                                                       const float* __restrict__ pl,
                                                       const int* __restrict__ valid,
                                                       float* __restrict__ out) {
    int p = blockIdx.x, b = blockIdx.y;
    int t = threadIdx.x;
    int k0 = 4 * t;

    int ix = (int)(pl[2 * p + 0] * WW); ix = min(max(ix, 0), WW - 1);
    int iy = (int)(pl[2 * p + 1] * HH); iy = min(max(iy, 0), HH - 1);
    int kp = iy * WW + ix;
    float rnp = rn[(size_t)b * HW + kp];

    float4 d  = *(const float4*)&dot[((size_t)b * NP + p) * HW + k0];
    float4 rk = *(const float4*)&rn[(size_t)b * HW + k0];

    float val[4];
    val[0] = d.x * rk.x * rnp;
    val[1] = d.y * rk.y * rnp;
    val[2] = d.z * rk.z * rnp;
    val[3] = d.w * rk.w * rnp;

    float mn = fminf(fminf(val[0], val[1]), fminf(val[2], val[3]));
    float mx = fmaxf(fmaxf(val[0], val[1]), fmaxf(val[2], val[3]));
#pragma unroll
    for (int off = 32; off; off >>= 1) {
        mn = fminf(mn, __shfl_xor(mn, off));
        mx = fmaxf(mx, __shfl_xor(mx, off));
    }
    __shared__ float smn[4], smx[4];
    int wave = t >> 6;
    if ((t & 63) == 0) { smn[wave] = mn; smx[wave] = mx; }
    __syncthreads();
    mn = fminf(fminf(smn[0], smn[1]), fminf(smn[2], smn[3]));
    mx = fmaxf(fmaxf(smx[0], smx[1]), fmaxf(smx[2], smx[3]));

    bool vld = valid[p] != 0;
    float4 o;
    o.x = vld ? (val[0] - mn) / mx : 0.f;
    o.y = vld ? (val[1] - mn) / mx : 0.f;
    o.z = vld ? (val[2] - mn) / mx : 0.f;
    o.w = vld ? (val[3] - mn) / mx : 0.f;
    *(float4*)&out[((size_t)b * NP + p) * HW + k0] = o;
}

// ---------------------------------------------------------------------------
extern "C" void kernel_launch(void* const* d_in, const int* in_sizes, int n_in,
                              void* d_out, int out_size, void* d_ws, size_t ws_size,
                              hipStream_t stream) {
    const float* fea = (const float*)d_in[0];
    const float* pl  = (const float*)d_in[1];
    const int* valid = (const int*)d_in[2];
    float* out = (float*)d_out;

    unsigned short* qbf = (unsigned short*)d_ws;                 // 4 MiB
    float* np2 = (float*)(qbf + (size_t)BB * NP * CC);           // 4 MiB
    float* rn  = np2 + (size_t)NCH * BB * HW;                    // 64 KiB
    float* dot = rn + (size_t)BB * HW;                           // 4 MiB

    prep_kernel<<<dim3(NCH, BB), 256, 0, stream>>>(fea, pl, qbf, np2);
    nred_kernel<<<dim3(BB), 256, 0, stream>>>(np2, rn);
    gemm_kernel<<<dim3(HW / KB, BB), 256, 0, stream>>>(fea, qbf, dot);
    finalize_kernel<<<dim3(NP, BB), 256, 0, stream>>>(dot, rn, pl, valid, out);
}